// Round 10
// baseline (388.627 us; speedup 1.0000x reference)
//
#include <hip/hip_runtime.h>
#include <cstddef>
#include <cstdint>

#define F_IN 128
#define D1   256   // HEADS*HID
#define HEADS 4
#define HID   64
#define OUT_C 32
#define NEG   0.2f

typedef unsigned short ushort_t;
typedef __attribute__((ext_vector_type(8))) short short8;
typedef __attribute__((ext_vector_type(4))) float f32x4;
typedef __attribute__((ext_vector_type(4))) unsigned short ushort4v;
typedef __attribute__((ext_vector_type(8))) unsigned short ushort8v;

__device__ __forceinline__ float bu2f(ushort_t u) {
  return __uint_as_float(((unsigned)u) << 16);
}
__device__ __forceinline__ ushort_t f2bu(float f) {
  unsigned u = __float_as_uint(f);
  return (ushort_t)((u + 0x7FFF + ((u >> 16) & 1)) >> 16);   // RNE
}

// ---- weight prep: Bt[nn][k] = concat(Wl,Wr) transposed to N-major, bf16 ----
__global__ void prep_b1_k(const float* __restrict__ Wl, const float* __restrict__ Wr,
                          const float* __restrict__ bl, const float* __restrict__ br,
                          ushort_t* __restrict__ Bt, float* __restrict__ biasc) {
  int i = blockIdx.x * blockDim.x + threadIdx.x;   // 512*128
  int nn = i >> 7, k = i & 127;
  float v = (nn < D1) ? Wl[(size_t)k * D1 + nn] : Wr[(size_t)k * D1 + (nn - D1)];
  Bt[(size_t)nn * F_IN + k] = f2bu(v);
  if (k == 0) biasc[nn] = (nn < D1) ? bl[nn] : br[nn - D1];
}

__global__ void prep_b2_k(const float* __restrict__ Wl, const float* __restrict__ Wr,
                          const float* __restrict__ bl, const float* __restrict__ br,
                          ushort_t* __restrict__ Bt, float* __restrict__ biasc) {
  int i = blockIdx.x * blockDim.x + threadIdx.x;   // 64*256
  int nn = i >> 8, k = i & 255;
  float v = (nn < OUT_C) ? Wl[(size_t)k * OUT_C + nn] : Wr[(size_t)k * OUT_C + (nn - OUT_C)];
  Bt[(size_t)nn * D1 + k] = f2bu(v);
  if (k == 0) biasc[nn] = (nn < OUT_C) ? bl[nn] : br[nn - OUT_C];
}

// ---- layer-1 GEMM, A-read-once: C[M,512] = bf16(fp32 A[M,128] @ Bt[512,128]^T + bias)
// A tile (128 rows x full K=128) staged ONCE as bf16; 8 B-tiles of 64 cols looped.
// LDS 52.2 KB -> 3 blocks/CU. grid.y == 1 -> no A re-fetch (R9 had 4x).
__global__ void gemm1_fused(const float* __restrict__ A, const ushort_t* __restrict__ Bt,
                            const float* __restrict__ biasc, ushort_t* __restrict__ C,
                            int M) {
  __shared__ ushort_t As[128][136];
  __shared__ ushort_t Bs[64][136];
  const int tid = threadIdx.x;
  const int wave = tid >> 6, lane = tid & 63;
  const int wm = wave & 1, wn = wave >> 1;       // 2x2 waves; wave tile 64 x 32
  const int quad = lane >> 4, l16 = lane & 15;
  const int m0 = blockIdx.x * 128;
  // stage A (fp32 -> bf16 in-register): 128 rows x 16 chunks(8)
  for (int i = tid; i < 128 * 16; i += 256) {
    int r = i >> 4, ch = i & 15;
    int gr = m0 + r;
    f32x4 v0 = {}, v1 = {};
    if (gr < M) {
      const float* p = A + (size_t)gr * 128 + ch * 8;
      v0 = *(const f32x4*)p;
      v1 = *(const f32x4*)(p + 4);
    }
    short8 o;
    o[0] = (short)f2bu(v0[0]); o[1] = (short)f2bu(v0[1]);
    o[2] = (short)f2bu(v0[2]); o[3] = (short)f2bu(v0[3]);
    o[4] = (short)f2bu(v1[0]); o[5] = (short)f2bu(v1[1]);
    o[6] = (short)f2bu(v1[2]); o[7] = (short)f2bu(v1[3]);
    *(short8*)(&As[r][ch * 8]) = o;
  }
  __syncthreads();
  for (int nt = 0; nt < 8; ++nt) {
    for (int i = tid; i < 64 * 16; i += 256) {
      int r = i >> 4, ch = i & 15;
      *(short8*)(&Bs[r][ch * 8]) =
          *(const short8*)(Bt + ((nt * 64 + r) << 7) + ch * 8);
    }
    __syncthreads();
    f32x4 acc[4][2] = {};
#pragma unroll
    for (int ks = 0; ks < 128; ks += 32) {
      short8 af[4], bfr[2];
#pragma unroll
      for (int mi = 0; mi < 4; ++mi)
        af[mi] = *(const short8*)(&As[wm * 64 + mi * 16 + l16][ks + quad * 8]);
#pragma unroll
      for (int ni = 0; ni < 2; ++ni)
        bfr[ni] = *(const short8*)(&Bs[wn * 32 + ni * 16 + l16][ks + quad * 8]);
#pragma unroll
      for (int mi = 0; mi < 4; ++mi)
#pragma unroll
        for (int ni = 0; ni < 2; ++ni)
          acc[mi][ni] = __builtin_amdgcn_mfma_f32_16x16x32_bf16(af[mi], bfr[ni],
                                                                acc[mi][ni], 0, 0, 0);
    }
#pragma unroll
    for (int mi = 0; mi < 4; ++mi) {
#pragma unroll
      for (int r = 0; r < 4; ++r) {
        int grow = m0 + wm * 64 + mi * 16 + quad * 4 + r;
        if (grow >= M) continue;
#pragma unroll
        for (int ni = 0; ni < 2; ++ni) {
          int gcol = nt * 64 + wn * 32 + ni * 16 + l16;
          C[(size_t)grow * 512 + gcol] = f2bu(acc[mi][ni][r] + biasc[gcol]);
        }
      }
    }
    __syncthreads();   // protect Bs before next tile's staging
  }
}

// ---- generic bf16 MFMA GEMM (NT), used for layer 2 (grid.y==1, no refetch) ----
template <int WM, int WN, int BK>
__global__ void mfma_gemm(const ushort_t* __restrict__ A16, const ushort_t* __restrict__ Bt,
                          const float* __restrict__ biasc, ushort_t* __restrict__ C,
                          int M, int N, int K) {
  constexpr int BM = WM * 64, BN = WN * 64;
  constexpr int LD = BK + 8;
  constexpr int CPR = BK / 8;
  __shared__ ushort_t As[BM][LD];
  __shared__ ushort_t Bs[BN][LD];
  const int tid = threadIdx.x;
  const int wave = tid >> 6, lane = tid & 63;
  const int wm = wave % WM, wn = wave / WM;
  const int quad = lane >> 4, l16 = lane & 15;
  const int m0 = blockIdx.x * BM, n0 = blockIdx.y * BN;
  const int nth = WM * WN * 64;
  f32x4 acc[4][4] = {};
  for (int k0 = 0; k0 < K; k0 += BK) {
    for (int i = tid; i < BM * CPR; i += nth) {
      int r = i / CPR, ch = i % CPR;
      int gr = m0 + r;
      short8 v = {};
      if (gr < M) v = *(const short8*)(A16 + (size_t)gr * K + k0 + ch * 8);
      *(short8*)(&As[r][ch * 8]) = v;
    }
    for (int i = tid; i < BN * CPR; i += nth) {
      int r = i / CPR, ch = i % CPR;
      short8 v = {};
      if (n0 + r < N) v = *(const short8*)(Bt + (size_t)(n0 + r) * K + k0 + ch * 8);
      *(short8*)(&Bs[r][ch * 8]) = v;
    }
    __syncthreads();
#pragma unroll
    for (int ks = 0; ks < BK; ks += 32) {
      short8 af[4], bfr[4];
#pragma unroll
      for (int mi = 0; mi < 4; ++mi)
        af[mi] = *(const short8*)(&As[wm * 64 + mi * 16 + l16][ks + quad * 8]);
#pragma unroll
      for (int ni = 0; ni < 4; ++ni)
        bfr[ni] = *(const short8*)(&Bs[wn * 64 + ni * 16 + l16][ks + quad * 8]);
#pragma unroll
      for (int mi = 0; mi < 4; ++mi)
#pragma unroll
        for (int ni = 0; ni < 4; ++ni)
          acc[mi][ni] = __builtin_amdgcn_mfma_f32_16x16x32_bf16(af[mi], bfr[ni],
                                                                acc[mi][ni], 0, 0, 0);
    }
    __syncthreads();
  }
#pragma unroll
  for (int mi = 0; mi < 4; ++mi) {
#pragma unroll
    for (int r = 0; r < 4; ++r) {
      int grow = m0 + wm * 64 + mi * 16 + quad * 4 + r;
      if (grow >= M) continue;
#pragma unroll
      for (int ni = 0; ni < 4; ++ni) {
        int gcol = n0 + wn * 64 + ni * 16 + l16;
        if (gcol < N) C[(size_t)grow * N + gcol] = f2bu(acc[mi][ni][r] + biasc[gcol]);
      }
    }
  }
}

// ================= CSR build (counting sort by dst) =================
__global__ void hist_k(const int* __restrict__ dst, int* __restrict__ deg, int e) {
  int i = blockIdx.x * blockDim.x + threadIdx.x;
  if (i < e) atomicAdd(&deg[dst[i]], 1);
}

__global__ void scan_block_k(const int* __restrict__ deg, int* __restrict__ row_ptr,
                             int* __restrict__ bsum, int n) {
  __shared__ int s[1024];
  int i = blockIdx.x * 1024 + threadIdx.x;
  int v = (i < n) ? deg[i] : 0;
  s[threadIdx.x] = v;
  __syncthreads();
  for (int off = 1; off < 1024; off <<= 1) {
    int t = (threadIdx.x >= off) ? s[threadIdx.x - off] : 0;
    __syncthreads();
    s[threadIdx.x] += t;
    __syncthreads();
  }
  if (i < n) row_ptr[i + 1] = s[threadIdx.x];
  if (threadIdx.x == 1023) bsum[blockIdx.x] = s[1023];
}

__global__ void scan_bsum_k(int* __restrict__ bsum, int nb) {
  __shared__ int s[128];
  int v = (threadIdx.x < nb) ? bsum[threadIdx.x] : 0;
  s[threadIdx.x] = v;
  __syncthreads();
  for (int off = 1; off < 128; off <<= 1) {
    int t = (threadIdx.x >= off) ? s[threadIdx.x - off] : 0;
    __syncthreads();
    s[threadIdx.x] += t;
    __syncthreads();
  }
  if (threadIdx.x < nb) bsum[threadIdx.x] = s[threadIdx.x] - v;  // exclusive
}

// final row_ptr AND cursor init in one pass
__global__ void add_off_k(int* __restrict__ row_ptr, const int* __restrict__ bsum,
                          int* __restrict__ cursor, int n) {
  int i = blockIdx.x * blockDim.x + threadIdx.x;
  if (i == 0) { row_ptr[0] = 0; cursor[0] = 0; }
  if (i < n) {
    int v = row_ptr[i + 1] + bsum[i >> 10];
    row_ptr[i + 1] = v;
    if (i + 1 < n) cursor[i + 1] = v;
  }
}

__global__ void fill_k(const int* __restrict__ src, const int* __restrict__ dst,
                       const float* __restrict__ eattr, int* __restrict__ cursor,
                       int2* __restrict__ csr, int e) {
  int i = blockIdx.x * blockDim.x + threadIdx.x;
  if (i >= e) return;
  int p = atomicAdd(&cursor[dst[i]], 1);
  csr[p] = make_int2(src[i], __float_as_int(eattr[i]));
}

// ========== fused GATv2 layer 1: 2 nodes/wave, 32 lanes/node, 8 ch/lane ==========
// C1 row: [xl(256)|xr(256)] bf16. cb=(lane&31)*8; head=(lane&31)>>3;
// butterfly masks 1,2,4 reduce within the 8-lane head group. 16B gathers.
__global__ void gat1_k(const int* __restrict__ row_ptr, const int2* __restrict__ csr,
                       const ushort_t* __restrict__ C1,
                       const float* __restrict__ We, const float* __restrict__ att,
                       const float* __restrict__ bias, ushort_t* __restrict__ h1, int n) {
  int lane = threadIdx.x & 63;
  int node = (int)((((size_t)blockIdx.x * blockDim.x + threadIdx.x)) >> 5);
  if (node >= n) return;
  int cb = (lane & 31) * 8;
  ushort8v xr8 = *(const ushort8v*)(C1 + (node << 9) + 256 + cb);
  f32x4 w0 = *(const f32x4*)(We + cb),  w1 = *(const f32x4*)(We + cb + 4);
  f32x4 a0 = *(const f32x4*)(att + cb), a1 = *(const f32x4*)(att + cb + 4);
  float xrr[8], Wev[8], attv[8], acc[8];
  float esum = 0.f;
#pragma unroll
  for (int j = 0; j < 4; ++j) {
    Wev[j] = w0[j]; Wev[j + 4] = w1[j];
    attv[j] = a0[j]; attv[j + 4] = a1[j];
  }
#pragma unroll
  for (int j = 0; j < 8; ++j) { xrr[j] = bu2f(xr8[j]); acc[j] = 0.f; }
  int p = row_ptr[node], p1 = row_ptr[node + 1];
  for (; p + 2 <= p1; p += 2) {
    int2 e0 = csr[p], e1 = csr[p + 1];
    ushort8v g0 = *(const ushort8v*)(C1 + (e0.x << 9) + cb);
    ushort8v g1 = *(const ushort8v*)(C1 + (e1.x << 9) + cb);
    float wg0 = __int_as_float(e0.y), wg1 = __int_as_float(e1.y);
    float xv0[8], xv1[8], v0 = 0.f, v1 = 0.f;
#pragma unroll
    for (int j = 0; j < 8; ++j) {
      xv0[j] = bu2f(g0[j]);
      float m = xv0[j] + xrr[j] + wg0 * Wev[j];
      m = m > 0.f ? m : NEG * m;
      v0 += m * attv[j];
      xv1[j] = bu2f(g1[j]);
      float q = xv1[j] + xrr[j] + wg1 * Wev[j];
      q = q > 0.f ? q : NEG * q;
      v1 += q * attv[j];
    }
    v0 += __shfl_xor(v0, 1, 64); v1 += __shfl_xor(v1, 1, 64);
    v0 += __shfl_xor(v0, 2, 64); v1 += __shfl_xor(v1, 2, 64);
    v0 += __shfl_xor(v0, 4, 64); v1 += __shfl_xor(v1, 4, 64);
    float eh0 = __expf(v0), eh1 = __expf(v1);   // no max-shift: logits bounded
    esum += eh0 + eh1;
#pragma unroll
    for (int j = 0; j < 8; ++j) acc[j] += eh0 * xv0[j] + eh1 * xv1[j];
  }
  if (p < p1) {
    int2 e0 = csr[p];
    ushort8v g0 = *(const ushort8v*)(C1 + (e0.x << 9) + cb);
    float wg0 = __int_as_float(e0.y);
    float xv0[8], v0 = 0.f;
#pragma unroll
    for (int j = 0; j < 8; ++j) {
      xv0[j] = bu2f(g0[j]);
      float m = xv0[j] + xrr[j] + wg0 * Wev[j];
      m = m > 0.f ? m : NEG * m;
      v0 += m * attv[j];
    }
    v0 += __shfl_xor(v0, 1, 64);
    v0 += __shfl_xor(v0, 2, 64);
    v0 += __shfl_xor(v0, 4, 64);
    float eh0 = __expf(v0);
    esum += eh0;
#pragma unroll
    for (int j = 0; j < 8; ++j) acc[j] += eh0 * xv0[j];
  }
  f32x4 b0 = *(const f32x4*)(bias + cb), b1 = *(const f32x4*)(bias + cb + 4);
  float inv = 1.f / (esum + 1e-16f);
  ushort8v o;
#pragma unroll
  for (int j = 0; j < 8; ++j) {
    float bb = j < 4 ? b0[j] : b1[j - 4];
    float t = acc[j] * inv + bb;
    o[j] = f2bu(t > 0.f ? t : 0.f);   // fused relu
  }
  *(ushort8v*)(h1 + (node << 8) + cb) = o;
}

// ========== fused GATv2 layer 2: 8 lanes/node, 4 ch/lane, edge loop x4 ==========
__global__ void gat2_k(const int* __restrict__ row_ptr, const int2* __restrict__ csr,
                       const ushort_t* __restrict__ C2,
                       const float* __restrict__ We, const float* __restrict__ att,
                       const float* __restrict__ bias, float* __restrict__ out, int n) {
  size_t t = (size_t)blockIdx.x * blockDim.x + threadIdx.x;
  int node = (int)(t >> 3);
  int g = (int)(t & 7);
  if (node >= n) return;
  int cb = g * 4;
  ushort4v xr4 = *(const ushort4v*)(C2 + (node << 6) + 32 + cb);
  f32x4 wv = *(const f32x4*)(We + cb);
  f32x4 av = *(const f32x4*)(att + cb);
  float xrr[4], acc[4] = {0.f, 0.f, 0.f, 0.f};
  float esum = 0.f;
#pragma unroll
  for (int j = 0; j < 4; ++j) xrr[j] = bu2f(xr4[j]);
  int p = row_ptr[node], p1 = row_ptr[node + 1];
  for (; p + 4 <= p1; p += 4) {
    int2 ee[4];
#pragma unroll
    for (int u = 0; u < 4; ++u) ee[u] = csr[p + u];
    ushort4v xl4[4];
#pragma unroll
    for (int u = 0; u < 4; ++u)
      xl4[u] = *(const ushort4v*)(C2 + (ee[u].x << 6) + cb);
    float xv[4][4], v[4];
#pragma unroll
    for (int u = 0; u < 4; ++u) {
      float wgt = __int_as_float(ee[u].y);
      v[u] = 0.f;
#pragma unroll
      for (int j = 0; j < 4; ++j) {
        xv[u][j] = bu2f(xl4[u][j]);
        float m = xv[u][j] + xrr[j] + wgt * wv[j];
        m = m > 0.f ? m : NEG * m;
        v[u] += m * av[j];
      }
    }
#pragma unroll
    for (int u = 0; u < 4; ++u) {
      v[u] += __shfl_xor(v[u], 1, 64);
      v[u] += __shfl_xor(v[u], 2, 64);
      v[u] += __shfl_xor(v[u], 4, 64);
    }
#pragma unroll
    for (int u = 0; u < 4; ++u) {
      float eh = __expf(v[u]);
      esum += eh;
#pragma unroll
      for (int j = 0; j < 4; ++j) acc[j] += eh * xv[u][j];
    }
  }
  for (; p < p1; ++p) {
    int2 ed = csr[p];
    float wgt = __int_as_float(ed.y);
    ushort4v xl4 = *(const ushort4v*)(C2 + (ed.x << 6) + cb);
    float xv[4], v = 0.f;
#pragma unroll
    for (int j = 0; j < 4; ++j) {
      xv[j] = bu2f(xl4[j]);
      float m = xv[j] + xrr[j] + wgt * wv[j];
      m = m > 0.f ? m : NEG * m;
      v += m * av[j];
    }
    v += __shfl_xor(v, 1, 64);
    v += __shfl_xor(v, 2, 64);
    v += __shfl_xor(v, 4, 64);
    float eh = __expf(v);
    esum += eh;
#pragma unroll
    for (int j = 0; j < 4; ++j) acc[j] += eh * xv[j];
  }
  f32x4 bv = *(const f32x4*)(bias + cb);
  float inv = 1.f / (esum + 1e-16f);
  f32x4 ov;
#pragma unroll
  for (int j = 0; j < 4; ++j) ov[j] = acc[j] * inv + bv[j];
  *(f32x4*)(out + (size_t)node * OUT_C + cb) = ov;
}

extern "C" void kernel_launch(void* const* d_in, const int* in_sizes, int n_in,
                              void* d_out, int out_size, void* d_ws, size_t ws_size,
                              hipStream_t stream) {
  const float* x     = (const float*)d_in[0];
  const int*   eidx  = (const int*)d_in[1];
  const float* eattr = (const float*)d_in[2];
  const float* Wl1 = (const float*)d_in[3];
  const float* bl1 = (const float*)d_in[4];
  const float* Wr1 = (const float*)d_in[5];
  const float* br1 = (const float*)d_in[6];
  const float* We1 = (const float*)d_in[7];
  const float* att1 = (const float*)d_in[8];
  const float* b1  = (const float*)d_in[9];
  const float* Wl2 = (const float*)d_in[10];
  const float* bl2 = (const float*)d_in[11];
  const float* Wr2 = (const float*)d_in[12];
  const float* br2 = (const float*)d_in[13];
  const float* We2 = (const float*)d_in[14];
  const float* att2 = (const float*)d_in[15];
  const float* b2  = (const float*)d_in[16];

  const int n = in_sizes[0] / F_IN;   // 100000
  const int e = in_sizes[2];          // 500000
  const int* src = eidx;
  const int* dst = eidx + e;
  float* out = (float*)d_out;

  // ---- workspace (~171 MB) ----
  char* w = (char*)d_ws;
  ushort_t* C1   = (ushort_t*)w;  w += (size_t)n * 512 * 2;      // 102.4 MB
  ushort_t* h1b  = (ushort_t*)w;  w += (size_t)n * D1 * 2;       // 51.2 MB
  ushort_t* C2   = (ushort_t*)w;  w += (size_t)n * 64 * 2;       // 12.8 MB
  ushort_t* Bt1  = (ushort_t*)w;  w += 512 * F_IN * 2;
  ushort_t* Bt2  = (ushort_t*)w;  w += 64 * D1 * 2;
  float* bias1c  = (float*)w;     w += 512 * 4;
  float* bias2c  = (float*)w;     w += 64 * 4;
  int2*  csr     = (int2*)w;      w += (size_t)e * 8;
  int*   row_ptr = (int*)w;       w += ((size_t)n + 1) * 4;
  int*   cursor  = (int*)w;       w += (size_t)n * 4;
  int*   bsum    = (int*)w;       w += 512;
  int*   deg = cursor;            // disjoint lifetimes

  dim3 blk(256);
  const int nb = (n + 1023) / 1024;   // 98 <= 128

  // ---- prep: transpose+convert weights ----
  prep_b1_k<<<(512 * 128) / 256, blk, 0, stream>>>(Wl1, Wr1, bl1, br1, Bt1, bias1c);
  prep_b2_k<<<(64 * 256) / 256, blk, 0, stream>>>(Wl2, Wr2, bl2, br2, Bt2, bias2c);

  // ---- CSR build ----
  hipMemsetAsync(deg, 0, (size_t)n * sizeof(int), stream);
  hist_k<<<(e + 255) / 256, blk, 0, stream>>>(dst, deg, e);
  scan_block_k<<<nb, 1024, 0, stream>>>(deg, row_ptr, bsum, n);
  scan_bsum_k<<<1, 128, 0, stream>>>(bsum, nb);
  add_off_k<<<(n + 255) / 256, blk, 0, stream>>>(row_ptr, bsum, cursor, n);
  fill_k<<<(e + 255) / 256, blk, 0, stream>>>(src, dst, eattr, cursor, csr, e);

  // ---- layer 1: C1 = x @ [Wl1|Wr1] + bias  (A read once; 8 B-tiles) ----
  gemm1_fused<<<(n + 127) / 128, blk, 0, stream>>>(x, Bt1, bias1c, C1, n);
  gat1_k<<<((size_t)n * 32 + 255) / 256, blk, 0, stream>>>(row_ptr, csr, C1,
                                                           We1, att1, b1, h1b, n);

  // ---- layer 2: C2 = h1 @ [Wl2|Wr2] + bias  (n x 256 @ 256 x 64) ----
  mfma_gemm<2, 1, 64><<<dim3((n + 127) / 128, 1), dim3(128), 0, stream>>>(
      h1b, Bt2, bias2c, C2, n, 64, D1);
  gat2_k<<<((size_t)n * 8 + 255) / 256, blk, 0, stream>>>(row_ptr, csr, C2,
                                                          We2, att2, b2, out, n);
}